// Round 1
// baseline (1092.817 us; speedup 1.0000x reference)
//
#include <hip/hip_runtime.h>
#include <math.h>

#define N_TOK 65536
#define K_CODE 8192
#define D_DIM 64

constexpr float DECAY = 0.9f;
constexpr float OMD = 0.1f;   // 1 - DECAY
constexpr float EPS = 1e-5f;

// ---- output layout (floats), per reference return order ----
constexpr int OUT_QE = 0;                      // quant_error scalar
constexpr int OUT_W  = 1;                      // new_weight [K, D]
constexpr int OUT_CS = 1 + K_CODE * D_DIM;     // new_cluster_size [K]
constexpr int OUT_EA = OUT_CS + K_CODE;        // new_embed_avg [K, D]

// ---- workspace layout (floats) ----
constexpr int WS_QE     = 0;                   // quant_error accumulator
constexpr int WS_NSUM   = 1;                   // sum of new_cluster_size
constexpr int WS_COUNTS = 16;                  // per-code counts [K]
constexpr int WS_EMBSUM = WS_COUNTS + K_CODE;  // segment sum of z [K, D]
constexpr int WS_CNORM  = WS_EMBSUM + K_CODE * D_DIM; // ||c_k||^2 [K]
constexpr int WS_ZERO   = WS_CNORM;            // floats to memset (cnorm is overwritten)

// ---------------------------------------------------------------------------
// ||c_k||^2 — one wave per code, lane = dim
__global__ void vq_cnorm(const float* __restrict__ w, float* __restrict__ cnorm) {
    const int wave = threadIdx.x >> 6;
    const int lane = threadIdx.x & 63;
    const int k = blockIdx.x * 4 + wave;
    const float v = w[(size_t)k * D_DIM + lane];
    float s = v * v;
#pragma unroll
    for (int m = 32; m >= 1; m >>= 1) s += __shfl_xor(s, m);
    if (lane == 0) cnorm[k] = s;
}

// ---------------------------------------------------------------------------
// Fused distance GEMM + argmin + segment-sum scatter.
// Block tile: 128 tokens x 128 codes. 256 threads, 8x8 register tile each.
// LDS tiles are XOR-swizzled at float4 granularity on (row>>3) so the 8-row
// strided b128 reads in the inner loop are bank-group conflict free.
__global__ __launch_bounds__(256, 2) void vq_argmin(
    const float* __restrict__ z, const float* __restrict__ w,
    float* __restrict__ ws)
{
    __shared__ __align__(16) float Zt[128 * 64];
    __shared__ __align__(16) float Wt[128 * 64];
    __shared__ float cn[128];
    __shared__ float znorm_s[128];
    __shared__ float mind_s[128];
    __shared__ int   tok_s[128];

    const int tid = threadIdx.x;
    const int tb = blockIdx.x * 128;
    const float* __restrict__ cnorm_g = ws + WS_CNORM;

    // ---- load Z tile (swizzled store) ----
#pragma unroll
    for (int q = 0; q < 8; ++q) {
        const int idx = q * 256 + tid;
        const int r = idx >> 4;
        const int c4 = idx & 15;
        const float4 v = *(const float4*)(z + (size_t)(tb + r) * D_DIM + c4 * 4);
        const int f = c4 ^ ((r >> 3) & 7);
        *(float4*)&Zt[r * 64 + f * 4] = v;
    }
    __syncthreads();

    // ---- per-token squared norm (sum order over swizzled layout is fine) ----
    if (tid < 128) {
        float s = 0.f;
#pragma unroll
        for (int d = 0; d < 64; ++d) { const float v = Zt[tid * 64 + d]; s += v * v; }
        znorm_s[tid] = s;
    }

    const int tx = tid & 15;        // code group
    const int ty = tid >> 4;        // token group
    const int r0 = ty * 8;          // token rows r0..r0+7
    const int c0 = tx * 8;          // code cols  c0..c0+7
    const int zsw = ty & 7;         // (r>>3)&7 for all 8 rows of this thread
    const int wsw = tx & 7;         // (c>>3)&7 for all 8 cols of this thread

    float minv[8];
    int   mini[8];
#pragma unroll
    for (int i = 0; i < 8; ++i) { minv[i] = 3.4e38f; mini[i] = 0; }

    for (int kt = 0; kt < K_CODE / 128; ++kt) {
        const int cb = kt * 128;
        __syncthreads();   // protect Wt/cn overwrite vs previous tile's readers
#pragma unroll
        for (int q = 0; q < 8; ++q) {
            const int idx = q * 256 + tid;
            const int r = idx >> 4;
            const int c4 = idx & 15;
            const float4 v = *(const float4*)(w + (size_t)(cb + r) * D_DIM + c4 * 4);
            const int f = c4 ^ ((r >> 3) & 7);
            *(float4*)&Wt[r * 64 + f * 4] = v;
        }
        if (tid < 128) cn[tid] = cnorm_g[cb + tid];
        __syncthreads();

        float acc[8][8] = {};
#pragma unroll
        for (int c4 = 0; c4 < 16; ++c4) {
            float4 za[8], wa[8];
#pragma unroll
            for (int i = 0; i < 8; ++i)
                za[i] = *(const float4*)&Zt[(r0 + i) * 64 + ((c4 ^ zsw) * 4)];
#pragma unroll
            for (int j = 0; j < 8; ++j)
                wa[j] = *(const float4*)&Wt[(c0 + j) * 64 + ((c4 ^ wsw) * 4)];
#pragma unroll
            for (int i = 0; i < 8; ++i)
#pragma unroll
                for (int j = 0; j < 8; ++j) {
                    acc[i][j] += za[i].x * wa[j].x;
                    acc[i][j] += za[i].y * wa[j].y;
                    acc[i][j] += za[i].z * wa[j].z;
                    acc[i][j] += za[i].w * wa[j].w;
                }
        }

        // dist = ||c||^2 - 2 z.c  (||z||^2 added at the end; constant per row).
        // k ascends, j ascends, strict '<' => first-min kept (matches argmin).
#pragma unroll
        for (int j = 0; j < 8; ++j) {
            const float c = cn[c0 + j];
            const int idx = cb + c0 + j;
#pragma unroll
            for (int i = 0; i < 8; ++i) {
                const float dist = c - 2.0f * acc[i][j];
                if (dist < minv[i]) { minv[i] = dist; mini[i] = idx; }
            }
        }
    }

    // ---- reduce across the 16 tx-lanes sharing each token row ----
#pragma unroll
    for (int i = 0; i < 8; ++i) {
        for (int m = 1; m < 16; m <<= 1) {
            const float ov = __shfl_xor(minv[i], m);
            const int   oi = __shfl_xor(mini[i], m);
            if (ov < minv[i] || (ov == minv[i] && oi < mini[i])) { minv[i] = ov; mini[i] = oi; }
        }
    }
    if (tx == 0) {
#pragma unroll
        for (int i = 0; i < 8; ++i) { mind_s[r0 + i] = minv[i]; tok_s[r0 + i] = mini[i]; }
    }
    __syncthreads();

    float* counts = ws + WS_COUNTS;
    float* embsum = ws + WS_EMBSUM;

    // quant_error partial + counts (threads 0..127, i.e. waves 0 and 1)
    if (tid < 128) {
        float qe = mind_s[tid] + znorm_s[tid];
#pragma unroll
        for (int m = 32; m >= 1; m >>= 1) qe += __shfl_xor(qe, m);
        if ((tid & 63) == 0) atomicAdd(ws + WS_QE, qe);
        atomicAdd(&counts[tok_s[tid]], 1.0f);
    }

    // segment-sum of z: wave-coalesced atomics, 64 consecutive floats per instr
    const int wv = tid >> 6, lane = tid & 63;
#pragma unroll
    for (int t = 0; t < 32; ++t) {
        const int r = wv * 32 + t;
        const int tk = tok_s[r];
        const int f4 = (lane >> 2) ^ ((r >> 3) & 7);
        const float zv = Zt[r * 64 + f4 * 4 + (lane & 3)];
        atomicAdd(&embsum[(size_t)tk * D_DIM + lane], zv);
    }
}

// ---------------------------------------------------------------------------
__global__ void vq_finalize_cs(const float* __restrict__ cluster_size,
                               float* __restrict__ ws, float* __restrict__ out)
{
    const int k = blockIdx.x * 256 + threadIdx.x;
    const float ncs = cluster_size[k] * DECAY + OMD * ws[WS_COUNTS + k];
    out[OUT_CS + k] = ncs;
    float s = ncs;
#pragma unroll
    for (int m = 32; m >= 1; m >>= 1) s += __shfl_xor(s, m);
    __shared__ float part[4];
    if ((threadIdx.x & 63) == 0) part[threadIdx.x >> 6] = s;
    __syncthreads();
    if (threadIdx.x == 0) {
        atomicAdd(ws + WS_NSUM, part[0] + part[1] + part[2] + part[3]);
        if (blockIdx.x == 0) out[OUT_QE] = ws[WS_QE] * (1.0f / N_TOK);
    }
}

__global__ void vq_finalize_w(const float* __restrict__ embed_avg,
                              const float* __restrict__ ws, float* __restrict__ out)
{
    const int idx = blockIdx.x * 256 + threadIdx.x;
    const int k = idx >> 6;
    const float nea = embed_avg[idx] * DECAY + OMD * ws[WS_EMBSUM + idx];
    out[OUT_EA + idx] = nea;
    const float n = ws[WS_NSUM];
    const float ncs = out[OUT_CS + k];
    const float sm = (ncs + EPS) / (n + K_CODE * EPS) * n;
    out[OUT_W + idx] = nea / sm;
}

// ---------------------------------------------------------------------------
extern "C" void kernel_launch(void* const* d_in, const int* in_sizes, int n_in,
                              void* d_out, int out_size, void* d_ws, size_t ws_size,
                              hipStream_t stream) {
    const float* z  = (const float*)d_in[0];
    const float* w  = (const float*)d_in[1];
    const float* cs = (const float*)d_in[2];
    const float* ea = (const float*)d_in[3];
    float* out = (float*)d_out;
    float* ws  = (float*)d_ws;

    // zero accumulators (ws is poisoned 0xAA before every call)
    hipMemsetAsync(d_ws, 0, (size_t)WS_ZERO * sizeof(float), stream);

    vq_cnorm<<<K_CODE / 4, 256, 0, stream>>>(w, ws + WS_CNORM);
    vq_argmin<<<N_TOK / 128, 256, 0, stream>>>(z, w, ws);
    vq_finalize_cs<<<K_CODE / 256, 256, 0, stream>>>(cs, ws, out);
    vq_finalize_w<<<K_CODE * D_DIM / 256, 256, 0, stream>>>(ea, ws, out);
}

// Round 2
// 310.813 us; speedup vs baseline: 3.5160x; 3.5160x over previous
//
#include <hip/hip_runtime.h>
#include <type_traits>

#define N_TOK 65536
#define K_CODE 8192
#define D_DIM 64

constexpr float DECAY = 0.9f;
constexpr float OMD = 0.1f;   // 1 - DECAY
constexpr float EPS = 1e-5f;

// ---- output layout (floats), per reference return order ----
constexpr int OUT_QE = 0;
constexpr int OUT_W  = 1;
constexpr int OUT_CS = 1 + K_CODE * D_DIM;
constexpr int OUT_EA = OUT_CS + K_CODE;

// ---- workspace layout (floats) ----
constexpr int WS_QE     = 0;
constexpr int WS_NSUM   = 1;
constexpr int WS_COUNTS = 16;
constexpr int WS_EMBSUM = WS_COUNTS + K_CODE;
constexpr int WS_CNORM  = WS_EMBSUM + K_CODE * D_DIM;
constexpr int WS_WHI    = WS_CNORM + K_CODE;            // ushort[K*64] (bf16 bits)
constexpr int WS_WLO    = WS_WHI + K_CODE * D_DIM / 2;  // ushort[K*64]
constexpr int WS_ZERO   = WS_CNORM;                     // floats to memset

typedef __attribute__((ext_vector_type(16))) float floatx16;
typedef __attribute__((ext_vector_type(8)))  short short8;
typedef __attribute__((ext_vector_type(8)))  __bf16 bf16x8;

// SFINAE hedge: gfx950 mfma bf16 builtin takes v8bf16 on newer clang, v8i16 per
// the HIP guide's example. Dispatch to whichever signature type-checks.
template <typename T, typename = void> struct mfma_takes : std::false_type {};
template <typename T>
struct mfma_takes<T, std::void_t<decltype(__builtin_amdgcn_mfma_f32_32x32x16_bf16(
    std::declval<T>(), std::declval<T>(), std::declval<floatx16>(), 0, 0, 0))>>
    : std::true_type {};

__device__ __forceinline__ floatx16 MFMA(short8 a, short8 b, floatx16 c) {
  if constexpr (mfma_takes<bf16x8>::value) {
    return __builtin_amdgcn_mfma_f32_32x32x16_bf16(
        __builtin_bit_cast(bf16x8, a), __builtin_bit_cast(bf16x8, b), c, 0, 0, 0);
  } else {
    return __builtin_amdgcn_mfma_f32_32x32x16_bf16(a, b, c, 0, 0, 0);
  }
}

__device__ __forceinline__ unsigned short bf16rne(float x) {
  unsigned int u = __float_as_uint(x);
  return (unsigned short)((u + 0x7FFFu + ((u >> 16) & 1u)) >> 16);
}

// ---------------------------------------------------------------------------
// Split W into bf16 hi/lo and compute exact fp32 ||c||^2. One wave per code.
__global__ void vq_prep(const float* __restrict__ w, float* __restrict__ ws) {
  const int tid = threadIdx.x;
  const int lane = tid & 63;
  const int k = blockIdx.x * 4 + (tid >> 6);
  const float v = w[(size_t)k * D_DIM + lane];
  const unsigned short h = bf16rne(v);
  const float hf = __uint_as_float((unsigned int)h << 16);
  const unsigned short l = bf16rne(v - hf);
  unsigned short* whi = (unsigned short*)(ws + WS_WHI);
  unsigned short* wlo = (unsigned short*)(ws + WS_WLO);
  whi[(size_t)k * D_DIM + lane] = h;
  wlo[(size_t)k * D_DIM + lane] = l;
  float s = v * v;
#pragma unroll
  for (int m = 32; m >= 1; m >>= 1) s += __shfl_xor(s, m);
  if (lane == 0) ws[WS_CNORM + k] = s;
}

// ---------------------------------------------------------------------------
// Fused split-bf16 MFMA distance + argmin + segment-sum scatter.
// Block = 4 waves x 32 tokens. Each wave: one 32-token strip vs all 8192 codes
// in 32-code chunks; 12 MFMAs/chunk (zh*wh + zh*wl + zl*wh over 4 k-steps).
// W chunks double-buffered in LDS, row stride 72 shorts (pad -> 2-way = free).
__global__ __launch_bounds__(256, 2) void vq_argmin(
    const float* __restrict__ z, float* __restrict__ ws)
{
  __shared__ __align__(16) unsigned short Wlds[2][2][32 * 72]; // [buf][hi/lo]
  __shared__ float mind_s[128];
  __shared__ int   tok_s[128];

  const int tid  = threadIdx.x;
  const int w    = tid >> 6;
  const int lane = tid & 63;
  const int m    = lane & 31;   // A row (token) and B col (code) within tile
  const int h    = lane >> 5;   // k-half selector
  const int tb   = blockIdx.x * 128;

  const unsigned short* whi = (const unsigned short*)(ws + WS_WHI);
  const unsigned short* wlo = (const unsigned short*)(ws + WS_WLO);
  const float* cnorm = ws + WS_CNORM;

  // ---- load this wave's 32 z rows, split to bf16 hi/lo fragments ----
  short8 ah[4], al[4];
  float znorm = 0.f;
  {
    const float* zrow = z + (size_t)(tb + w * 32 + m) * D_DIM + 8 * h;
#pragma unroll
    for (int s = 0; s < 4; ++s) {
      const float4 v0 = *(const float4*)(zrow + 16 * s);
      const float4 v1 = *(const float4*)(zrow + 16 * s + 4);
      const float vals[8] = {v0.x, v0.y, v0.z, v0.w, v1.x, v1.y, v1.z, v1.w};
#pragma unroll
      for (int j = 0; j < 8; ++j) {
        const float x = vals[j];
        const unsigned short hb = bf16rne(x);
        const float hf = __uint_as_float((unsigned int)hb << 16);
        const unsigned short lb = bf16rne(x - hf);
        ah[s][j] = (short)hb;
        al[s][j] = (short)lb;
        znorm += x * x;
      }
    }
    znorm += __shfl_xor(znorm, 32);   // other k-half of the same row
  }

  // ---- staging: thread covers (row sr, 16B granule sg) of the 32x128B chunk
  const int sr = m;
  const int sg = 2 * w + h;
  uint4 sthi, stlo;
  auto stage_load = [&](int c) {
    const size_t off = ((size_t)(c * 32 + sr)) * D_DIM + sg * 8;
    sthi = *(const uint4*)(whi + off);
    stlo = *(const uint4*)(wlo + off);
  };
  auto stage_write = [&](int c) {
    const int b = c & 1;
    *(uint4*)&Wlds[b][0][sr * 72 + sg * 8] = sthi;
    *(uint4*)&Wlds[b][1][sr * 72 + sg * 8] = stlo;
  };

  float minv[16];
  int   mini[16];
#pragma unroll
  for (int r = 0; r < 16; ++r) { minv[r] = 3.4e38f; mini[r] = 0; }

  const floatx16 kZero = {};

  stage_load(0);
  stage_write(0);
  __syncthreads();

  for (int c = 0; c < K_CODE / 32; ++c) {
    const int b = c & 1;
    const float cn = cnorm[c * 32 + m];          // exact fp32 ||c||^2
    if (c + 1 < K_CODE / 32) stage_load(c + 1);  // prefetch next chunk

    short8 bh[4], bl[4];
#pragma unroll
    for (int s = 0; s < 4; ++s) {
      bh[s] = *(const short8*)&Wlds[b][0][m * 72 + (2 * s + h) * 8];
      bl[s] = *(const short8*)&Wlds[b][1][m * 72 + (2 * s + h) * 8];
    }

    // two interleaved 6-deep MFMA chains for ILP
    floatx16 a0, a1;
    a0 = MFMA(ah[0], bh[0], kZero);
    a1 = MFMA(al[0], bh[0], kZero);
    a0 = MFMA(ah[1], bh[1], a0);
    a1 = MFMA(al[1], bh[1], a1);
    a0 = MFMA(ah[2], bh[2], a0);
    a1 = MFMA(al[2], bh[2], a1);
    a0 = MFMA(ah[3], bh[3], a0);
    a1 = MFMA(al[3], bh[3], a1);
    a0 = MFMA(ah[0], bl[0], a0);
    a1 = MFMA(ah[2], bl[2], a1);
    a0 = MFMA(ah[1], bl[1], a0);
    a1 = MFMA(ah[3], bl[3], a1);

    // dist = ||c||^2 - 2 z.c ; k ascending + strict '<' keeps first-min
    const int idxc = c * 32 + m;
#pragma unroll
    for (int r = 0; r < 16; ++r) {
      const float d = __builtin_fmaf(-2.f, a0[r] + a1[r], cn);
      if (d < minv[r]) { minv[r] = d; mini[r] = idxc; }
    }

    if (c + 1 < K_CODE / 32) stage_write(c + 1);
    __syncthreads();
  }

  // ---- reduce over the 32 lanes (cols) holding each row; first-index ties
#pragma unroll
  for (int r = 0; r < 16; ++r) {
#pragma unroll
    for (int mm = 1; mm < 32; mm <<= 1) {
      const float ov = __shfl_xor(minv[r], mm);
      const int   oi = __shfl_xor(mini[r], mm);
      if (ov < minv[r] || (ov == minv[r] && oi < mini[r])) { minv[r] = ov; mini[r] = oi; }
    }
  }
  // C/D layout: row = (r&3) + 8*(r>>2) + 4*h. One writer lane per row.
#pragma unroll
  for (int r = 0; r < 16; ++r) {
    const int mr = (r & 3) + 8 * (r >> 2) + 4 * h;
    if (m == mr) {
      tok_s[w * 32 + mr]  = mini[r];
      mind_s[w * 32 + mr] = minv[r] + znorm;   // full dist for quant_error
    }
  }
  __syncthreads();

  float* counts = ws + WS_COUNTS;
  float* embsum = ws + WS_EMBSUM;

  if (tid < 128) {
    float qe = mind_s[tid];
#pragma unroll
    for (int mm = 32; mm >= 1; mm >>= 1) qe += __shfl_xor(qe, mm);
    if ((tid & 63) == 0) atomicAdd(ws + WS_QE, qe);
    atomicAdd(&counts[tok_s[tid]], 1.0f);
  }

  // segment-sum of z: wave-coalesced atomics (64 consecutive floats/instr)
#pragma unroll 4
  for (int t = 0; t < 32; ++t) {
    const int row = w * 32 + t;
    const int tk = tok_s[row];
    const float zv = z[(size_t)(tb + row) * D_DIM + lane];
    atomicAdd(&embsum[(size_t)tk * D_DIM + lane], zv);
  }
}

// ---------------------------------------------------------------------------
__global__ void vq_finalize_cs(const float* __restrict__ cluster_size,
                               float* __restrict__ ws, float* __restrict__ out)
{
  const int k = blockIdx.x * 256 + threadIdx.x;
  const float ncs = cluster_size[k] * DECAY + OMD * ws[WS_COUNTS + k];
  out[OUT_CS + k] = ncs;
  float s = ncs;
#pragma unroll
  for (int m = 32; m >= 1; m >>= 1) s += __shfl_xor(s, m);
  __shared__ float part[4];
  if ((threadIdx.x & 63) == 0) part[threadIdx.x >> 6] = s;
  __syncthreads();
  if (threadIdx.x == 0) {
    atomicAdd(ws + WS_NSUM, part[0] + part[1] + part[2] + part[3]);
    if (blockIdx.x == 0) out[OUT_QE] = ws[WS_QE] * (1.0f / N_TOK);
  }
}

__global__ void vq_finalize_w(const float* __restrict__ embed_avg,
                              const float* __restrict__ ws, float* __restrict__ out)
{
  const int idx = blockIdx.x * 256 + threadIdx.x;
  const int k = idx >> 6;
  const float nea = embed_avg[idx] * DECAY + OMD * ws[WS_EMBSUM + idx];
  out[OUT_EA + idx] = nea;
  const float n = ws[WS_NSUM];
  const float ncs = out[OUT_CS + k];
  const float sm = (ncs + EPS) / (n + K_CODE * EPS) * n;
  out[OUT_W + idx] = nea / sm;
}

// ---------------------------------------------------------------------------
extern "C" void kernel_launch(void* const* d_in, const int* in_sizes, int n_in,
                              void* d_out, int out_size, void* d_ws, size_t ws_size,
                              hipStream_t stream) {
  const float* z  = (const float*)d_in[0];
  const float* w  = (const float*)d_in[1];
  const float* cs = (const float*)d_in[2];
  const float* ea = (const float*)d_in[3];
  float* out = (float*)d_out;
  float* ws  = (float*)d_ws;

  hipMemsetAsync(d_ws, 0, (size_t)WS_ZERO * sizeof(float), stream);

  vq_prep<<<K_CODE / 4, 256, 0, stream>>>(w, ws);
  vq_argmin<<<N_TOK / 128, 256, 0, stream>>>(z, ws);
  vq_finalize_cs<<<K_CODE / 256, 256, 0, stream>>>(cs, ws, out);
  vq_finalize_w<<<K_CODE * D_DIM / 256, 256, 0, stream>>>(ea, ws, out);
}